// Round 1
// baseline (363.608 us; speedup 1.0000x reference)
//
#include <hip/hip_runtime.h>

typedef __bf16 bf16;
typedef __attribute__((ext_vector_type(8))) __bf16 bf16x8;
typedef __attribute__((ext_vector_type(4))) __bf16 bf16x4;
typedef __attribute__((ext_vector_type(4))) float f32x4;

#define MFMA16(A, B, C) __builtin_amdgcn_mfma_f32_16x16x32_bf16(A, B, C, 0, 0, 0)

// ---------------------------------------------------------------------------
// Transpose + fp32->bf16 convert: out[N][K] = (bf16) in[K][N]
// ---------------------------------------------------------------------------
__global__ __launch_bounds__(256) void transpose_cvt_kernel(
    const float* __restrict__ in, bf16* __restrict__ out, int K, int N)
{
  __shared__ float tile[32][33];
  const int kt = blockIdx.y * 32;
  const int nt = blockIdx.x * 32;
  const int tx = threadIdx.x, ty = threadIdx.y;
#pragma unroll
  for (int j = 0; j < 4; ++j)
    tile[ty + j * 8][tx] = in[(size_t)(kt + ty + j * 8) * N + nt + tx];
  __syncthreads();
#pragma unroll
  for (int j = 0; j < 4; ++j)
    out[(size_t)(nt + ty + j * 8) * K + kt + tx] = (bf16)tile[tx][ty + j * 8];
}

// ---------------------------------------------------------------------------
// LayerNorm (eps=1e-3), fp32 in -> bf16 out. One block per row of 1024.
// ---------------------------------------------------------------------------
__global__ __launch_bounds__(256) void ln_kernel(
    const float* __restrict__ in, const float* __restrict__ gamma,
    const float* __restrict__ beta, bf16* __restrict__ out)
{
  const int row = blockIdx.x;
  const int t = threadIdx.x;
  const float4 v = ((const float4*)(in + (size_t)row * 1024))[t];
  float s = v.x + v.y + v.z + v.w;
  float sq = v.x * v.x + v.y * v.y + v.z * v.z + v.w * v.w;
#pragma unroll
  for (int m = 1; m < 64; m <<= 1) {
    s += __shfl_xor(s, m);
    sq += __shfl_xor(sq, m);
  }
  __shared__ float ssum[4], ssq[4];
  const int w = t >> 6;
  if ((t & 63) == 0) { ssum[w] = s; ssq[w] = sq; }
  __syncthreads();
  s = ssum[0] + ssum[1] + ssum[2] + ssum[3];
  sq = ssq[0] + ssq[1] + ssq[2] + ssq[3];
  const float mu = s * (1.0f / 1024.0f);
  const float var = sq * (1.0f / 1024.0f) - mu * mu;
  const float rs = rsqrtf(var + 1e-3f);
  const float4 g = ((const float4*)gamma)[t];
  const float4 b = ((const float4*)beta)[t];
  bf16x4 o;
  o[0] = (bf16)((v.x - mu) * rs * g.x + b.x);
  o[1] = (bf16)((v.y - mu) * rs * g.y + b.y);
  o[2] = (bf16)((v.z - mu) * rs * g.z + b.z);
  o[3] = (bf16)((v.w - mu) * rs * g.w + b.w);
  *(bf16x4*)(out + (size_t)row * 1024 + t * 4) = o;
}

// ---------------------------------------------------------------------------
// GEMM: C[M,N] = epilogue(A[M,K] @ Bt[N,K]^T + bias[N])
// EPI 0: bf16 out                1: bf16 relu out
// EPI 2: f32 out = acc+bias+resid   3: bf16 out, per-head transposed [b,h,d,t]
// 128x128 tile, BK=32, 256 threads (2x2 waves, 64x64 each), reg-prefetch.
// ---------------------------------------------------------------------------
template <int EPI>
__global__ __launch_bounds__(256) void gemm_bt_kernel(
    const bf16* __restrict__ A, const bf16* __restrict__ Bt,
    const float* __restrict__ bias, const float* __restrict__ resid,
    bf16* __restrict__ outb, float* __restrict__ outf,
    int M, int N, int K)
{
  __shared__ bf16 As[128][40];  // +8 pad: conflict-free ds_read_b128
  __shared__ bf16 Bs[128][40];
  const int tid = threadIdx.x;
  const int lane = tid & 63;
  const int w = tid >> 6;
  const int wr = w >> 1, wc = w & 1;
  const int g = lane >> 4, lr = lane & 15;
  const int brow = blockIdx.y * 128, bcol = blockIdx.x * 128;

  f32x4 acc[4][4] = {};

  const int srow = tid >> 1;
  const int scol = (tid & 1) * 16;
  const bf16* Ap = A + (size_t)(brow + srow) * K + scol;
  const bf16* Bp = Bt + (size_t)(bcol + srow) * K + scol;

  const int nk = K >> 5;
  bf16x8 pa0 = *(const bf16x8*)(Ap);
  bf16x8 pa1 = *(const bf16x8*)(Ap + 8);
  bf16x8 pb0 = *(const bf16x8*)(Bp);
  bf16x8 pb1 = *(const bf16x8*)(Bp + 8);

  for (int tstep = 0; tstep < nk; ++tstep) {
    *(bf16x8*)&As[srow][scol] = pa0;
    *(bf16x8*)&As[srow][scol + 8] = pa1;
    *(bf16x8*)&Bs[srow][scol] = pb0;
    *(bf16x8*)&Bs[srow][scol + 8] = pb1;
    __syncthreads();
    if (tstep + 1 < nk) {   // prefetch next K-tile into regs (hides HBM latency)
      const int k0 = (tstep + 1) << 5;
      pa0 = *(const bf16x8*)(Ap + k0);
      pa1 = *(const bf16x8*)(Ap + k0 + 8);
      pb0 = *(const bf16x8*)(Bp + k0);
      pb1 = *(const bf16x8*)(Bp + k0 + 8);
    }
    bf16x8 afr[4], bfr[4];
#pragma unroll
    for (int i = 0; i < 4; ++i)
      afr[i] = *(const bf16x8*)&As[wr * 64 + i * 16 + lr][g * 8];
#pragma unroll
    for (int j = 0; j < 4; ++j)
      bfr[j] = *(const bf16x8*)&Bs[wc * 64 + j * 16 + lr][g * 8];
#pragma unroll
    for (int i = 0; i < 4; ++i)
#pragma unroll
      for (int j = 0; j < 4; ++j)
        acc[i][j] = MFMA16(afr[i], bfr[j], acc[i][j]);
    __syncthreads();
  }

#pragma unroll
  for (int i = 0; i < 4; ++i) {
#pragma unroll
    for (int j = 0; j < 4; ++j) {
      const int r0 = brow + wr * 64 + i * 16 + g * 4;  // +reg -> output row
      const int c = bcol + wc * 64 + j * 16 + lr;      // output col
      const float bv = bias[c];
      if constexpr (EPI == 0) {
#pragma unroll
        for (int rr = 0; rr < 4; ++rr)
          outb[(size_t)(r0 + rr) * N + c] = (bf16)(acc[i][j][rr] + bv);
      } else if constexpr (EPI == 1) {
#pragma unroll
        for (int rr = 0; rr < 4; ++rr)
          outb[(size_t)(r0 + rr) * N + c] = (bf16)fmaxf(acc[i][j][rr] + bv, 0.0f);
      } else if constexpr (EPI == 2) {
#pragma unroll
        for (int rr = 0; rr < 4; ++rr) {
          const size_t idx = (size_t)(r0 + rr) * N + c;
          outf[idx] = acc[i][j][rr] + bv + resid[idx];
        }
      } else {  // EPI 3: V stored as [b][h][d][t] for attention PV operand
        const int bb = r0 >> 11, t0 = r0 & 2047;
        const int hh = c >> 6, dd = c & 63;
        bf16x4 pk;
#pragma unroll
        for (int rr = 0; rr < 4; ++rr) pk[rr] = (bf16)(acc[i][j][rr] + bv);
        *(bf16x4*)(outb + ((size_t)((bb * 16 + hh) * 64 + dd)) * 2048 + t0) = pk;
      }
    }
  }
}

// ---------------------------------------------------------------------------
// Causal flash attention. Grid (qtile=32, bh=32). Block: 4 waves, 64 q-rows.
// q,k: [4096 tokens][1024] bf16 ; vt: [b][h][64 d][2048 t] bf16
// ctx out: [4096][1024] bf16
// ---------------------------------------------------------------------------
__global__ __launch_bounds__(256) void attn_kernel(
    const bf16* __restrict__ q, const bf16* __restrict__ kmat,
    const bf16* __restrict__ vt, bf16* __restrict__ ctx)
{
  __shared__ bf16 Ks[64][72];       // [s][d], padded
  __shared__ bf16 Vs[64][72];       // [d][s], padded
  __shared__ bf16 Ps[4][64][20];    // per-wave P^T [s][q], padded
  const int qt = blockIdx.x;
  const int bh = blockIdx.y;
  const int b_ = bh >> 4, h_ = bh & 15;
  const int qb = qt * 64;
  const int tid = threadIdx.x;
  const int lane = tid & 63, w = tid >> 6;
  const int g = lane >> 4, lr = lane & 15;
  const int wq0 = qb + w * 16;  // this wave's first q row

  bf16x8 aq[2];
  {
    const bf16* qp = q + (size_t)(b_ * 2048 + wq0 + lr) * 1024 + h_ * 64 + g * 8;
    aq[0] = *(const bf16x8*)qp;
    aq[1] = *(const bf16x8*)(qp + 32);
  }

  f32x4 o[4] = {};
  float mrow[4] = {-1e30f, -1e30f, -1e30f, -1e30f};
  float lrow[4] = {0.f, 0.f, 0.f, 0.f};

  const int srow = tid >> 2;
  const int soff = (tid & 3) * 16;
  const bf16* kbase = kmat + (size_t)(b_ * 2048) * 1024 + h_ * 64;
  const bf16* vbase = vt + (size_t)(b_ * 16 + h_) * 64 * 2048;

  for (int s0 = 0; s0 <= qb; s0 += 64) {
    {
      const bf16* kp = kbase + (size_t)(s0 + srow) * 1024 + soff;
      bf16x8 t0 = *(const bf16x8*)kp;
      bf16x8 t1 = *(const bf16x8*)(kp + 8);
      *(bf16x8*)&Ks[srow][soff] = t0;
      *(bf16x8*)&Ks[srow][soff + 8] = t1;
      const bf16* vp = vbase + (size_t)srow * 2048 + s0 + soff;
      bf16x8 u0 = *(const bf16x8*)vp;
      bf16x8 u1 = *(const bf16x8*)(vp + 8);
      *(bf16x8*)&Vs[srow][soff] = u0;
      *(bf16x8*)&Vs[srow][soff + 8] = u1;
    }
    __syncthreads();

    // S = Q K^T
    f32x4 sc[4];
#pragma unroll
    for (int n = 0; n < 4; ++n) {
      f32x4 z = {};
#pragma unroll
      for (int kk = 0; kk < 2; ++kk) {
        bf16x8 bk = *(const bf16x8*)&Ks[n * 16 + lr][kk * 32 + g * 8];
        z = MFMA16(aq[kk], bk, z);
      }
      sc[n] = z;
    }

    const bool needmask = (s0 + 63 > wq0);
#pragma unroll
    for (int n = 0; n < 4; ++n)
#pragma unroll
      for (int r = 0; r < 4; ++r) {
        float sv = sc[n][r] * 0.125f;  // 1/sqrt(64)
        if (needmask && (s0 + n * 16 + lr > wq0 + g * 4 + r)) sv = -1e30f;
        sc[n][r] = sv;
      }

    // online softmax: row max over the 16 lanes holding this row's cols
    float pm[4];
#pragma unroll
    for (int r = 0; r < 4; ++r)
      pm[r] = fmaxf(fmaxf(sc[0][r], sc[1][r]), fmaxf(sc[2][r], sc[3][r]));
#pragma unroll
    for (int m = 1; m < 16; m <<= 1)
#pragma unroll
      for (int r = 0; r < 4; ++r) pm[r] = fmaxf(pm[r], __shfl_xor(pm[r], m));

    float alpha[4], rsum[4];
#pragma unroll
    for (int r = 0; r < 4; ++r) {
      const float mn = fmaxf(mrow[r], pm[r]);
      alpha[r] = __expf(mrow[r] - mn);
      mrow[r] = mn;
      rsum[r] = 0.f;
    }
#pragma unroll
    for (int n = 0; n < 4; ++n)
#pragma unroll
      for (int r = 0; r < 4; ++r) {
        const float p = __expf(sc[n][r] - mrow[r]);
        sc[n][r] = p;
        rsum[r] += p;
      }
#pragma unroll
    for (int m = 1; m < 16; m <<= 1)
#pragma unroll
      for (int r = 0; r < 4; ++r) rsum[r] += __shfl_xor(rsum[r], m);
#pragma unroll
    for (int r = 0; r < 4; ++r) lrow[r] = lrow[r] * alpha[r] + rsum[r];
#pragma unroll
    for (int n = 0; n < 4; ++n)
#pragma unroll
      for (int r = 0; r < 4; ++r) o[n][r] *= alpha[r];

    // write P^T to per-wave LDS (8B packs), reread as PV A-fragments
#pragma unroll
    for (int n = 0; n < 4; ++n) {
      bf16x4 pk;
#pragma unroll
      for (int r = 0; r < 4; ++r) pk[r] = (bf16)sc[n][r];
      *(bf16x4*)&Ps[w][n * 16 + lr][g * 4] = pk;
    }

#pragma unroll
    for (int kk = 0; kk < 2; ++kk) {
      bf16x8 ap;
#pragma unroll
      for (int j2 = 0; j2 < 8; ++j2) ap[j2] = Ps[w][kk * 32 + g * 8 + j2][lr];
#pragma unroll
      for (int n = 0; n < 4; ++n) {
        bf16x8 bv = *(const bf16x8*)&Vs[n * 16 + lr][kk * 32 + g * 8];
        o[n] = MFMA16(ap, bv, o[n]);
      }
    }
    __syncthreads();
  }

#pragma unroll
  for (int r = 0; r < 4; ++r) {
    const float inv = 1.0f / lrow[r];
#pragma unroll
    for (int n = 0; n < 4; ++n)
      ctx[(size_t)(b_ * 2048 + wq0 + g * 4 + r) * 1024 + h_ * 64 + n * 16 + lr] =
          (bf16)(o[n][r] * inv);
  }
}

// ---------------------------------------------------------------------------
extern "C" void kernel_launch(void* const* d_in, const int* in_sizes, int n_in,
                              void* d_out, int out_size, void* d_ws, size_t ws_size,
                              hipStream_t stream)
{
  (void)in_sizes; (void)n_in; (void)out_size; (void)ws_size;
  const float* x   = (const float*)d_in[0];
  const float* Wq  = (const float*)d_in[1];
  const float* bq  = (const float*)d_in[2];
  const float* Wk  = (const float*)d_in[3];
  const float* bk  = (const float*)d_in[4];
  const float* Wv  = (const float*)d_in[5];
  const float* bv  = (const float*)d_in[6];
  const float* Wo  = (const float*)d_in[7];
  const float* bo  = (const float*)d_in[8];
  const float* W1  = (const float*)d_in[9];
  const float* b1  = (const float*)d_in[10];
  const float* W2  = (const float*)d_in[11];
  const float* b2  = (const float*)d_in[12];
  const float* g1  = (const float*)d_in[13];
  const float* be1 = (const float*)d_in[14];
  const float* g2  = (const float*)d_in[15];
  const float* be2 = (const float*)d_in[16];
  float* out = (float*)d_out;

  char* ws = (char*)d_ws;
  const size_t MB = 1024 * 1024;
  bf16* wq_t = (bf16*)(ws + 0 * MB);   // [1024][1024]
  bf16* wk_t = (bf16*)(ws + 2 * MB);
  bf16* wv_t = (bf16*)(ws + 4 * MB);
  bf16* wo_t = (bf16*)(ws + 6 * MB);
  bf16* w1_t = (bf16*)(ws + 8 * MB);   // [4096][1024]
  bf16* w2_t = (bf16*)(ws + 16 * MB);  // [1024][4096]
  bf16* h1   = (bf16*)(ws + 24 * MB);  // [4096][1024]
  bf16* qbuf = (bf16*)(ws + 32 * MB);  // [4096][1024]
  bf16* kbuf = (bf16*)(ws + 40 * MB);  // [4096][1024]
  bf16* vtb  = (bf16*)(ws + 48 * MB);  // [2][16][64][2048]
  bf16* ctx  = (bf16*)(ws + 56 * MB);  // [4096][1024]
  bf16* h2   = (bf16*)(ws + 64 * MB);  // [4096][1024]
  bf16* ff1  = (bf16*)(ws + 24 * MB);  // [4096][4096], overlays h1/q/k/vT (dead)

  const dim3 tb(32, 8);
  transpose_cvt_kernel<<<dim3(32, 32), tb, 0, stream>>>(Wq, wq_t, 1024, 1024);
  transpose_cvt_kernel<<<dim3(32, 32), tb, 0, stream>>>(Wk, wk_t, 1024, 1024);
  transpose_cvt_kernel<<<dim3(32, 32), tb, 0, stream>>>(Wv, wv_t, 1024, 1024);
  transpose_cvt_kernel<<<dim3(32, 32), tb, 0, stream>>>(Wo, wo_t, 1024, 1024);
  transpose_cvt_kernel<<<dim3(128, 32), tb, 0, stream>>>(W1, w1_t, 1024, 4096);
  transpose_cvt_kernel<<<dim3(32, 128), tb, 0, stream>>>(W2, w2_t, 4096, 1024);

  ln_kernel<<<4096, 256, 0, stream>>>(x, g1, be1, h1);

  gemm_bt_kernel<0><<<dim3(8, 32), 256, 0, stream>>>(h1, wq_t, bq, nullptr, qbuf, nullptr, 4096, 1024, 1024);
  gemm_bt_kernel<0><<<dim3(8, 32), 256, 0, stream>>>(h1, wk_t, bk, nullptr, kbuf, nullptr, 4096, 1024, 1024);
  gemm_bt_kernel<3><<<dim3(8, 32), 256, 0, stream>>>(h1, wv_t, bv, nullptr, vtb, nullptr, 4096, 1024, 1024);

  attn_kernel<<<dim3(32, 32), 256, 0, stream>>>(qbuf, kbuf, vtb, ctx);

  // x2 = x + ctx@Wo + bo  -> stored in d_out (fp32)
  gemm_bt_kernel<2><<<dim3(8, 32), 256, 0, stream>>>(ctx, wo_t, bo, x, nullptr, out, 4096, 1024, 1024);

  ln_kernel<<<4096, 256, 0, stream>>>(out, g2, be2, h2);

  gemm_bt_kernel<1><<<dim3(32, 32), 256, 0, stream>>>(h2, w1_t, b1, nullptr, ff1, nullptr, 4096, 4096, 1024);

  // out = x2 + ff1@W2 + b2  (in-place read+write of d_out, one thread/element)
  gemm_bt_kernel<2><<<dim3(8, 32), 256, 0, stream>>>(ff1, w2_t, b2, out, nullptr, out, 4096, 1024, 4096);
}

// Round 2
// 277.049 us; speedup vs baseline: 1.3124x; 1.3124x over previous
//
#include <hip/hip_runtime.h>

typedef __bf16 bf16;
typedef __attribute__((ext_vector_type(8))) __bf16 bf16x8;
typedef __attribute__((ext_vector_type(4))) __bf16 bf16x4;
typedef __attribute__((ext_vector_type(4))) float f32x4;

#define MFMA16(A, B, C) __builtin_amdgcn_mfma_f32_16x16x32_bf16(A, B, C, 0, 0, 0)

// ---------------------------------------------------------------------------
// Transpose + fp32->bf16 convert: out[N][K] = (bf16) in[K][N]
// ---------------------------------------------------------------------------
__global__ __launch_bounds__(256) void transpose_cvt_kernel(
    const float* __restrict__ in, bf16* __restrict__ out, int K, int N)
{
  __shared__ float tile[32][33];
  const int kt = blockIdx.y * 32;
  const int nt = blockIdx.x * 32;
  const int tx = threadIdx.x, ty = threadIdx.y;
#pragma unroll
  for (int j = 0; j < 4; ++j)
    tile[ty + j * 8][tx] = in[(size_t)(kt + ty + j * 8) * N + nt + tx];
  __syncthreads();
#pragma unroll
  for (int j = 0; j < 4; ++j)
    out[(size_t)(nt + ty + j * 8) * K + kt + tx] = (bf16)tile[tx][ty + j * 8];
}

// ---------------------------------------------------------------------------
// LayerNorm (eps=1e-3), fp32 in -> bf16 out. One block per row of 1024.
// ---------------------------------------------------------------------------
__global__ __launch_bounds__(256) void ln_kernel(
    const float* __restrict__ in, const float* __restrict__ gamma,
    const float* __restrict__ beta, bf16* __restrict__ out)
{
  const int row = blockIdx.x;
  const int t = threadIdx.x;
  const float4 v = ((const float4*)(in + (size_t)row * 1024))[t];
  float s = v.x + v.y + v.z + v.w;
  float sq = v.x * v.x + v.y * v.y + v.z * v.z + v.w * v.w;
#pragma unroll
  for (int m = 1; m < 64; m <<= 1) {
    s += __shfl_xor(s, m);
    sq += __shfl_xor(sq, m);
  }
  __shared__ float ssum[4], ssq[4];
  const int w = t >> 6;
  if ((t & 63) == 0) { ssum[w] = s; ssq[w] = sq; }
  __syncthreads();
  s = ssum[0] + ssum[1] + ssum[2] + ssum[3];
  sq = ssq[0] + ssq[1] + ssq[2] + ssq[3];
  const float mu = s * (1.0f / 1024.0f);
  const float var = sq * (1.0f / 1024.0f) - mu * mu;
  const float rs = rsqrtf(var + 1e-3f);
  const float4 g = ((const float4*)gamma)[t];
  const float4 b = ((const float4*)beta)[t];
  bf16x4 o;
  o[0] = (bf16)((v.x - mu) * rs * g.x + b.x);
  o[1] = (bf16)((v.y - mu) * rs * g.y + b.y);
  o[2] = (bf16)((v.z - mu) * rs * g.z + b.z);
  o[3] = (bf16)((v.w - mu) * rs * g.w + b.w);
  *(bf16x4*)(out + (size_t)row * 1024 + t * 4) = o;
}

// ---------------------------------------------------------------------------
// GEMM: C[M,N] = epilogue(A[M,K] @ Bt[N,K]^T + bias)
// BN=128: 2x2 waves of 64x64.  BN=64: 2x2 waves of 64x32.
// EPI 1: bf16 relu -> out0
// EPI 2: f32 out = acc + bias0 + resid -> outf
// EPI 4: fused QKV: col<1024 -> out0(+bias0); <2048 -> out1(+bias1);
//        else V stored per-head transposed [b][h][d][t] -> out2(+bias2)
// ---------------------------------------------------------------------------
template <int BN, int EPI>
__global__ __launch_bounds__(256) void gemm_bt(
    const bf16* __restrict__ A, const bf16* __restrict__ Bt,
    const float* __restrict__ bias0, const float* __restrict__ bias1,
    const float* __restrict__ bias2, const float* __restrict__ resid,
    bf16* __restrict__ out0, bf16* __restrict__ out1, bf16* __restrict__ out2,
    float* __restrict__ outf, int M, int N, int K)
{
  constexpr int WN = BN / 2;   // wave tile cols
  constexpr int NJ = WN / 16;  // col fragments per wave
  __shared__ bf16 As[128][40];
  __shared__ bf16 Bs[BN][40];
  const int tid = threadIdx.x;
  const int lane = tid & 63, w = tid >> 6;
  const int wr = w >> 1, wc = w & 1;
  const int g = lane >> 4, lr = lane & 15;
  const int brow = blockIdx.y * 128, bcol = blockIdx.x * BN;

  f32x4 acc[4][NJ] = {};

  const int srowA = tid >> 1, scolA = (tid & 1) * 16;
  const bf16* Ap = A + (size_t)(brow + srowA) * K + scolA;
  const int srowB = (BN == 128) ? (tid >> 1) : (tid >> 2);
  const int scolB = (BN == 128) ? ((tid & 1) * 16) : ((tid & 3) * 8);
  const bf16* Bp = Bt + (size_t)(bcol + srowB) * K + scolB;

  const int nk = K >> 5;
  bf16x8 pa0 = *(const bf16x8*)(Ap);
  bf16x8 pa1 = *(const bf16x8*)(Ap + 8);
  bf16x8 pb0 = *(const bf16x8*)(Bp);
  bf16x8 pb1{};
  if constexpr (BN == 128) pb1 = *(const bf16x8*)(Bp + 8);

  for (int t = 0; t < nk; ++t) {
    *(bf16x8*)&As[srowA][scolA] = pa0;
    *(bf16x8*)&As[srowA][scolA + 8] = pa1;
    *(bf16x8*)&Bs[srowB][scolB] = pb0;
    if constexpr (BN == 128) *(bf16x8*)&Bs[srowB][scolB + 8] = pb1;
    __syncthreads();
    if (t + 1 < nk) {
      const int k0 = (t + 1) << 5;
      pa0 = *(const bf16x8*)(Ap + k0);
      pa1 = *(const bf16x8*)(Ap + k0 + 8);
      pb0 = *(const bf16x8*)(Bp + k0);
      if constexpr (BN == 128) pb1 = *(const bf16x8*)(Bp + k0 + 8);
    }
    bf16x8 afr[4], bfr[NJ];
#pragma unroll
    for (int i = 0; i < 4; ++i)
      afr[i] = *(const bf16x8*)&As[wr * 64 + i * 16 + lr][g * 8];
#pragma unroll
    for (int j = 0; j < NJ; ++j)
      bfr[j] = *(const bf16x8*)&Bs[wc * WN + j * 16 + lr][g * 8];
#pragma unroll
    for (int i = 0; i < 4; ++i)
#pragma unroll
      for (int j = 0; j < NJ; ++j)
        acc[i][j] = MFMA16(afr[i], bfr[j], acc[i][j]);
    __syncthreads();
  }

#pragma unroll
  for (int i = 0; i < 4; ++i) {
#pragma unroll
    for (int j = 0; j < NJ; ++j) {
      const int r0 = brow + wr * 64 + i * 16 + g * 4;
      const int c = bcol + wc * WN + j * 16 + lr;
      if constexpr (EPI == 1) {
        const float bv = bias0[c];
#pragma unroll
        for (int rr = 0; rr < 4; ++rr)
          out0[(size_t)(r0 + rr) * N + c] = (bf16)fmaxf(acc[i][j][rr] + bv, 0.0f);
      } else if constexpr (EPI == 2) {
        const float bv = bias0[c];
#pragma unroll
        for (int rr = 0; rr < 4; ++rr) {
          const size_t idx = (size_t)(r0 + rr) * N + c;
          outf[idx] = acc[i][j][rr] + bv + resid[idx];
        }
      } else {  // EPI 4: fused QKV
        const int sub = c >> 10;       // block-uniform (128-col tiles)
        const int c1 = c & 1023;
        if (sub == 0) {
          const float bv = bias0[c1];
#pragma unroll
          for (int rr = 0; rr < 4; ++rr)
            out0[(size_t)(r0 + rr) * 1024 + c1] = (bf16)(acc[i][j][rr] + bv);
        } else if (sub == 1) {
          const float bv = bias1[c1];
#pragma unroll
          for (int rr = 0; rr < 4; ++rr)
            out1[(size_t)(r0 + rr) * 1024 + c1] = (bf16)(acc[i][j][rr] + bv);
        } else {
          const float bv = bias2[c1];
          const int bb = r0 >> 11, t0 = r0 & 2047;
          const int hh = c1 >> 6, dd = c1 & 63;
          bf16x4 pk;
#pragma unroll
          for (int rr = 0; rr < 4; ++rr) pk[rr] = (bf16)(acc[i][j][rr] + bv);
          *(bf16x4*)(out2 + ((size_t)((bb * 16 + hh) * 64 + dd)) * 2048 + t0) = pk;
        }
      }
    }
  }
}

// ---------------------------------------------------------------------------
// Causal flash attention, S^T formulation: per lane one q-row (q = lane&15).
// Grid (32,32): qt = (bx+by)&31 for CU load balance. Block: 4 waves x 16 q.
// q,k: [4096][1024] bf16 ; vt: [b][h][64 d][2048 t] bf16 ; ctx: [4096][1024]
// K/V LDS tiles [64 rows][64 bf16] with XOR-swizzled 16B slots (T2/G4).
// ---------------------------------------------------------------------------
__global__ __launch_bounds__(256) void attn_kernel(
    const bf16* __restrict__ q, const bf16* __restrict__ kmat,
    const bf16* __restrict__ vt, bf16* __restrict__ ctx)
{
  __shared__ bf16 Ks[64 * 64];
  __shared__ bf16 Vs[64 * 64];
  __shared__ bf16 Pq[4][16][88];  // per-wave P [q][s], stride 88
  const int qt = (blockIdx.x + blockIdx.y) & 31;
  const int bh = blockIdx.y;
  const int b_ = bh >> 4, h_ = bh & 15;
  const int qb = qt * 64;
  const int tid = threadIdx.x;
  const int lane = tid & 63, w = tid >> 6;
  const int g = lane >> 4, lr = lane & 15;
  const int qrow = qb + w * 16 + lr;  // this lane's q row (S^T layout)

  // Q fragment (B-operand): lane holds Q[qrow][g*8 + kk*32 + 0..7]
  bf16x8 qf[2];
  {
    const bf16* qp = q + (size_t)(b_ * 2048 + qrow) * 1024 + h_ * 64 + g * 8;
    qf[0] = *(const bf16x8*)qp;
    qf[1] = *(const bf16x8*)(qp + 32);
  }

  f32x4 o[4] = {};
  float m = -1e30f, l = 0.f;

  const int srow = tid >> 2;            // staging row 0..63
  const int c16 = (tid & 3) * 16;       // staging col (elements)
  const int rb = srow * 128;            // row byte base in LDS tile
  const int sw = (srow & 7) << 4;       // XOR swizzle
  const bf16* kbase = kmat + (size_t)(b_ * 2048) * 1024 + h_ * 64;
  const bf16* vbase = vt + (size_t)(b_ * 16 + h_) * 64 * 2048;
  const bf16* kp0 = kbase + (size_t)srow * 1024 + c16;
  const bf16* vp0 = vbase + (size_t)srow * 2048 + c16;

  bf16x8 k0 = *(const bf16x8*)kp0;
  bf16x8 k1 = *(const bf16x8*)(kp0 + 8);
  bf16x8 v0 = *(const bf16x8*)vp0;
  bf16x8 v1 = *(const bf16x8*)(vp0 + 8);

  for (int s0 = 0; s0 <= qb; s0 += 64) {
    *(bf16x8*)((char*)Ks + ((rb + c16 * 2) ^ sw)) = k0;
    *(bf16x8*)((char*)Ks + ((rb + c16 * 2 + 16) ^ sw)) = k1;
    *(bf16x8*)((char*)Vs + ((rb + c16 * 2) ^ sw)) = v0;
    *(bf16x8*)((char*)Vs + ((rb + c16 * 2 + 16) ^ sw)) = v1;
    __syncthreads();
    if (s0 < qb) {  // prefetch next K/V tile into regs during compute
      const bf16* kp = kp0 + (size_t)(s0 + 64) * 1024;
      k0 = *(const bf16x8*)kp;
      k1 = *(const bf16x8*)(kp + 8);
      const bf16* vp = vp0 + (s0 + 64);
      v0 = *(const bf16x8*)vp;
      v1 = *(const bf16x8*)(vp + 8);
    }

    // S^T = K @ Q^T : lane holds S[q=qrow][s = s0 + 16n + 4g + r]
    f32x4 st[4];
#pragma unroll
    for (int n = 0; n < 4; ++n) {
      f32x4 z = {};
#pragma unroll
      for (int kk = 0; kk < 2; ++kk) {
        const int row = n * 16 + lr;
        bf16x8 ak = *(const bf16x8*)((char*)Ks +
            ((row * 128 + kk * 64 + g * 16) ^ ((lr & 7) << 4)));
        z = MFMA16(ak, qf[kk], z);
      }
      st[n] = z;
    }

    const bool needmask = (s0 == qb);
    float pm = -1e30f;
#pragma unroll
    for (int n = 0; n < 4; ++n)
#pragma unroll
      for (int r = 0; r < 4; ++r) {
        float sv = st[n][r] * 0.125f;  // 1/sqrt(64)
        if (needmask && (s0 + n * 16 + g * 4 + r > qrow)) sv = -1e30f;
        st[n][r] = sv;
        pm = fmaxf(pm, sv);
      }
    pm = fmaxf(pm, __shfl_xor(pm, 16));
    pm = fmaxf(pm, __shfl_xor(pm, 32));
    const float mn = fmaxf(m, pm);
    const float alpha = __expf(m - mn);
    m = mn;

    float rs = 0.f;
#pragma unroll
    for (int n = 0; n < 4; ++n) {
      bf16x4 pk;
#pragma unroll
      for (int r = 0; r < 4; ++r) {
        const float p = __expf(st[n][r] - mn);
        rs += p;
        pk[r] = (bf16)p;
      }
      *(bf16x4*)&Pq[w][lr][n * 16 + g * 4] = pk;  // P[q][s], s consecutive
    }
    rs += __shfl_xor(rs, 16);
    rs += __shfl_xor(rs, 32);
    l = l * alpha + rs;

    // broadcast alpha to O layout (row q_local = 4g + r)
    float av[4];
#pragma unroll
    for (int r = 0; r < 4; ++r) av[r] = __shfl(alpha, g * 4 + r);
#pragma unroll
    for (int n = 0; n < 4; ++n)
#pragma unroll
      for (int r = 0; r < 4; ++r) o[n][r] *= av[r];

    // PV: A = P fragment (vectorized), B = Vt fragment
    bf16x8 pa[2];
#pragma unroll
    for (int kk = 0; kk < 2; ++kk)
      pa[kk] = *(const bf16x8*)&Pq[w][lr][kk * 32 + g * 8];
#pragma unroll
    for (int n = 0; n < 4; ++n) {
      const int row = n * 16 + lr;
#pragma unroll
      for (int kk = 0; kk < 2; ++kk) {
        bf16x8 bv = *(const bf16x8*)((char*)Vs +
            ((row * 128 + kk * 64 + g * 16) ^ ((lr & 7) << 4)));
        o[n] = MFMA16(pa[kk], bv, o[n]);
      }
    }
    __syncthreads();
  }

  float lq[4];
#pragma unroll
  for (int r = 0; r < 4; ++r) lq[r] = __shfl(l, g * 4 + r);
#pragma unroll
  for (int r = 0; r < 4; ++r) {
    const float inv = 1.0f / lq[r];
#pragma unroll
    for (int n = 0; n < 4; ++n)
      ctx[(size_t)(b_ * 2048 + qb + w * 16 + g * 4 + r) * 1024 + h_ * 64 + n * 16 + lr] =
          (bf16)(o[n][r] * inv);
  }
}

// ---------------------------------------------------------------------------
extern "C" void kernel_launch(void* const* d_in, const int* in_sizes, int n_in,
                              void* d_out, int out_size, void* d_ws, size_t ws_size,
                              hipStream_t stream)
{
  (void)in_sizes; (void)n_in; (void)out_size; (void)ws_size;
  const float* x   = (const float*)d_in[0];
  const float* Wq  = (const float*)d_in[1];
  const float* bq  = (const float*)d_in[2];
  const float* Wk  = (const float*)d_in[3];
  const float* bk  = (const float*)d_in[4];
  const float* Wv  = (const float*)d_in[5];
  const float* bv  = (const float*)d_in[6];
  const float* Wo  = (const float*)d_in[7];
  const float* bo  = (const float*)d_in[8];
  const float* W1  = (const float*)d_in[9];
  const float* b1  = (const float*)d_in[10];
  const float* W2  = (const float*)d_in[11];
  const float* b2  = (const float*)d_in[12];
  const float* g1  = (const float*)d_in[13];
  const float* be1 = (const float*)d_in[14];
  const float* g2  = (const float*)d_in[15];
  const float* be2 = (const float*)d_in[16];
  float* out = (float*)d_out;

  char* ws = (char*)d_ws;
  const size_t MB = 1024 * 1024;
  bf16* wqkv_t = (bf16*)(ws + 0 * MB);  // [3072][1024]: wq|wk|wv contiguous
  bf16* wq_t = (bf16*)(ws + 0 * MB);
  bf16* wk_t = (bf16*)(ws + 2 * MB);
  bf16* wv_t = (bf16*)(ws + 4 * MB);
  bf16* wo_t = (bf16*)(ws + 6 * MB);
  bf16* w1_t = (bf16*)(ws + 8 * MB);   // [4096][1024]
  bf16* w2_t = (bf16*)(ws + 16 * MB);  // [1024][4096]
  bf16* h1   = (bf16*)(ws + 24 * MB);  // [4096][1024]
  bf16* qbuf = (bf16*)(ws + 32 * MB);  // [4096][1024]
  bf16* kbuf = (bf16*)(ws + 40 * MB);  // [4096][1024]
  bf16* vtb  = (bf16*)(ws + 48 * MB);  // [2][16][64][2048]
  bf16* ctx  = (bf16*)(ws + 56 * MB);  // [4096][1024]
  bf16* h2   = (bf16*)(ws + 64 * MB);  // [4096][1024]
  bf16* ff1  = (bf16*)(ws + 24 * MB);  // [4096][4096], overlays h1/q/k/vtb (dead)

  const dim3 tb(32, 8);
  transpose_cvt_kernel<<<dim3(32, 32), tb, 0, stream>>>(Wq, wq_t, 1024, 1024);
  transpose_cvt_kernel<<<dim3(32, 32), tb, 0, stream>>>(Wk, wk_t, 1024, 1024);
  transpose_cvt_kernel<<<dim3(32, 32), tb, 0, stream>>>(Wv, wv_t, 1024, 1024);
  transpose_cvt_kernel<<<dim3(32, 32), tb, 0, stream>>>(Wo, wo_t, 1024, 1024);
  transpose_cvt_kernel<<<dim3(128, 32), tb, 0, stream>>>(W1, w1_t, 1024, 4096);
  transpose_cvt_kernel<<<dim3(32, 128), tb, 0, stream>>>(W2, w2_t, 4096, 1024);

  ln_kernel<<<4096, 256, 0, stream>>>(x, g1, be1, h1);

  // fused QKV: [4096,1024] @ [1024,3072] -> q,k,v(transposed)
  gemm_bt<128, 4><<<dim3(24, 32), 256, 0, stream>>>(
      h1, wqkv_t, bq, bk, bv, nullptr, qbuf, kbuf, vtb, nullptr, 4096, 3072, 1024);

  attn_kernel<<<dim3(32, 32), 256, 0, stream>>>(qbuf, kbuf, vtb, ctx);

  // x2 = x + ctx@Wo + bo -> d_out (fp32)
  gemm_bt<64, 2><<<dim3(16, 32), 256, 0, stream>>>(
      ctx, wo_t, bo, nullptr, nullptr, x, nullptr, nullptr, nullptr, out, 4096, 1024, 1024);

  ln_kernel<<<4096, 256, 0, stream>>>(out, g2, be2, h2);

  gemm_bt<128, 1><<<dim3(32, 32), 256, 0, stream>>>(
      h2, w1_t, b1, nullptr, nullptr, nullptr, ff1, nullptr, nullptr, nullptr, 4096, 4096, 1024);

  // out = x2 + ff1@W2 + b2 (in-place read+write of d_out, 1 thread/element)
  gemm_bt<64, 2><<<dim3(16, 32), 256, 0, stream>>>(
      ff1, w2_t, b2, nullptr, nullptr, out, nullptr, nullptr, nullptr, out, 4096, 1024, 4096);
}